// Round 6
// baseline (259.168 us; speedup 1.0000x reference)
//
#include <hip/hip_runtime.h>

// Weighted BP decoder, (3,6)-regular Tanner graph.
// Check r owns edges 6r..6r+5 (row-major nonzeros of H) -> check-side extrinsic
// products are in-register prefix/suffix products (c_prod_idx unused).
//
// Messages in log2 domain: d = c2v/ln2. With z = exp2(a), t = tanh(a*ln2/2)
// = (z-1)/(z+1); extrinsic product p = A/B with A = prod(z-1), B = prod(z+1)
// (all-but-one). Then
//   d_new = log2(B + kappa*A) - log2(B - kappa*A)
// -> per edge-row transcendentals: exp2 + 2*log2 (tanh/atanh never formed).
// Exponent clamped at 24 (== z <= 2^24): 5-way products <= 2^120, and
// B >= |A| keeps both log args >= (1-kappa)*B > 0.
//
// R6 = R5 + bank-conflict-breaking pad. R5's stride-6 layout made gather
// addresses 24t+const dwords -> lanes t==t' (mod 4) collide on one 4-bank
// group (16 accesses/bank vs the 8 floor for b128) -> SQ_LDS_BANK_CONFLICT
// 16.2M cycles. Pad one v4f slot every 32 edges: slot(e) = e + (e>>5).
// Enumeration shows 16 same-phase lanes then spread ~2 per bank-quad.
// LDS: 3168 slots * 16 B = 50688 B (+1.5 KB only; 2 blocks/CU still fit,
// known-good at 49152*2=98304, known-bad at 57344*2).

namespace {

typedef float v4f __attribute__((ext_vector_type(4)));

constexpr int T      = 512;   // threads/block == checks
constexpr int ROWS   = 4;     // batch rows per block (v4f-packed)
constexpr int EEDG   = 3072;
constexpr int NSLOT  = EEDG + (EEDG >> 5);   // 3168 padded slots
constexpr int NVAR   = 1024;
constexpr int NITER  = 10;
constexpr int BATCH  = 8192;
constexpr int NOUT   = 512;   // N - M outputs per row

constexpr float LOG2E = 1.4426950408889634f;
constexpr float LN2   = 0.6931471805599453f;
constexpr float KAPPA = 0.999995f;
constexpr float ACLMP = 24.0f;   // exp2 arg clamp == z <= 2^24

__device__ __forceinline__ float fast_exp2(float x) { return __builtin_amdgcn_exp2f(x); }
__device__ __forceinline__ float fast_log2(float x) { return __builtin_amdgcn_logf(x); }
__device__ __forceinline__ float fast_rcp (float x) { return __builtin_amdgcn_rcpf(x); }

__device__ __forceinline__ int pslot(int e) { return e + (e >> 5); }

__global__ __launch_bounds__(T, 2)
void bp_decode(const float* __restrict__ llr,
               const float* __restrict__ w_iter,
               const float* __restrict__ llr_iter,
               const float* __restrict__ w_final,
               const float* __restrict__ llr_final,
               const int*  __restrict__ v_sum_idx,
               const int*  __restrict__ edge_var,
               const int*  __restrict__ final_idx,
               float* __restrict__ out)
{
    __shared__ v4f Ad[NSLOT];   // 50688 B

    const int  tid = threadIdx.x;
    const long b0  = (long)blockIdx.x * ROWS;

    // ---- init: d = 0 over all padded slots ----
    #pragma unroll
    for (int k = 0; k < 7; ++k) {
        int idx = k * T + tid;
        if (idx < NSLOT) Ad[idx] = (v4f)(0.f);
    }

    // ---- static per-thread graph data (my check = tid, edges 6*tid..6*tid+5) ----
    unsigned nbp[6];    // my 12 neighbor-edge padded slots, 2x16b packed
    unsigned varp[3];   // my 6 variable ids, 2x16b packed
    v4f      Lpre[6];   // llr (4 rows) * LOG2E per edge
    unsigned ownp[6];   // padded slots of my own 6 edges (pads may interleave)
    {
        const int4* p = (const int4*)(v_sum_idx + 12 * tid);  // 48B-aligned
        int4 q0 = p[0], q1 = p[1], q2 = p[2];
        nbp[0] = (unsigned)pslot(q0.x) | ((unsigned)pslot(q0.y) << 16);
        nbp[1] = (unsigned)pslot(q0.z) | ((unsigned)pslot(q0.w) << 16);
        nbp[2] = (unsigned)pslot(q1.x) | ((unsigned)pslot(q1.y) << 16);
        nbp[3] = (unsigned)pslot(q1.z) | ((unsigned)pslot(q1.w) << 16);
        nbp[4] = (unsigned)pslot(q2.x) | ((unsigned)pslot(q2.y) << 16);
        nbp[5] = (unsigned)pslot(q2.z) | ((unsigned)pslot(q2.w) << 16);
    }
    #pragma unroll
    for (int k = 0; k < 6; ++k) ownp[k] = (unsigned)pslot(6 * tid + k);
    {
        int var[6];
        const int2* p = (const int2*)(edge_var + 6 * tid);    // 24B-aligned
        int2 q0 = p[0], q1 = p[1], q2 = p[2];
        var[0]=q0.x; var[1]=q0.y; var[2]=q1.x; var[3]=q1.y; var[4]=q2.x; var[5]=q2.y;
        #pragma unroll
        for (int i = 0; i < 3; ++i)
            varp[i] = (unsigned)var[2*i] | ((unsigned)var[2*i+1] << 16);
        #pragma unroll
        for (int j = 0; j < 6; ++j) {
            v4f L;
            L.x = llr[(b0 + 0) * NVAR + var[j]];
            L.y = llr[(b0 + 1) * NVAR + var[j]];
            L.z = llr[(b0 + 2) * NVAR + var[j]];
            L.w = llr[(b0 + 3) * NVAR + var[j]];
            Lpre[j] = L * LOG2E;
        }
    }

    // prefetch iteration 0 uniforms
    float w[12], lv[6];
    {
        const float* p = w_iter + 12 * tid;
        float4 a = ((const float4*)p)[0], b = ((const float4*)p)[1], c = ((const float4*)p)[2];
        w[0]=a.x; w[1]=a.y; w[2]=a.z;  w[3]=a.w;
        w[4]=b.x; w[5]=b.y; w[6]=b.z;  w[7]=b.w;
        w[8]=c.x; w[9]=c.y; w[10]=c.z; w[11]=c.w;
        #pragma unroll
        for (int i = 0; i < 3; ++i) {
            unsigned q = varp[i];
            lv[2*i]   = llr_iter[q & 0xffffu];
            lv[2*i+1] = llr_iter[q >> 16];
        }
    }

    __syncthreads();

    #pragma unroll 2
    for (int it = 0; it < NITER; ++it) {
        // accumulators seeded with channel term; LDS gathers folded in
        // immediately (peak live small -> no spills)
        v4f a[6];
        #pragma unroll
        for (int j = 0; j < 6; ++j) a[j] = Lpre[j] * lv[j];
        #pragma unroll
        for (int i = 0; i < 6; ++i) {
            unsigned p  = nbp[i];
            v4f ga = Ad[p & 0xffffu];     // ds_read_b128
            v4f gb = Ad[p >> 16];
            a[i] = a[i] + w[2*i] * ga + w[2*i+1] * gb;   // pk fma
        }

        __syncthreads();   // all gathers landed before anyone overwrites in place

        // prefetch next iteration's uniforms; latency hides under transc phase
        {
            const int itn = (it + 1 < NITER) ? it + 1 : it;   // clamp, no OOB
            const float* p = w_iter + itn * (EEDG * 2) + 12 * tid;
            float4 qa = ((const float4*)p)[0], qb = ((const float4*)p)[1], qc = ((const float4*)p)[2];
            const float* lit = llr_iter + itn * NVAR;
            float lvn[6];
            #pragma unroll
            for (int i = 0; i < 3; ++i) {
                unsigned q = varp[i];
                lvn[2*i]   = lit[q & 0xffffu];
                lvn[2*i+1] = lit[q >> 16];
            }

            // z-domain check update (uses current w, lv via a[])
            v4f zm[6], zp[6];
            #pragma unroll
            for (int j = 0; j < 6; ++j) {
                v4f aa = __builtin_elementwise_min(a[j], (v4f)(ACLMP));
                v4f z;
                z.x = fast_exp2(aa.x);
                z.y = fast_exp2(aa.y);
                z.z = fast_exp2(aa.z);
                z.w = fast_exp2(aa.w);
                zm[j] = z - 1.f;
                zp[j] = z + 1.f;
            }
            v4f A[6], B[6];
            {
                v4f P1=zm[0], P2=P1*zm[1], P3=P2*zm[2], P4=P3*zm[3], P5=P4*zm[4];
                v4f S4=zm[5], S3=S4*zm[4], S2=S3*zm[3], S1=S2*zm[2], S0=S1*zm[1];
                A[0]=S0; A[1]=P1*S1; A[2]=P2*S2; A[3]=P3*S3; A[4]=P4*S4; A[5]=P5;
            }
            {
                v4f P1=zp[0], P2=P1*zp[1], P3=P2*zp[2], P4=P3*zp[3], P5=P4*zp[4];
                v4f S4=zp[5], S3=S4*zp[4], S2=S3*zp[3], S1=S2*zp[2], S0=S1*zp[1];
                B[0]=S0; B[1]=P1*S1; B[2]=P2*S2; B[3]=P3*S3; B[4]=P4*S4; B[5]=P5;
            }
            #pragma unroll
            for (int j = 0; j < 6; ++j) {
                v4f num = KAPPA * A[j] + B[j];    // pk fma
                v4f den = B[j] - KAPPA * A[j];    // pk fma
                v4f d;
                d.x = fast_log2(num.x) - fast_log2(den.x);
                d.y = fast_log2(num.y) - fast_log2(den.y);
                d.z = fast_log2(num.z) - fast_log2(den.z);
                d.w = fast_log2(num.w) - fast_log2(den.w);
                Ad[ownp[j]] = d;                  // ds_write_b128
            }

            // rotate prefetched uniforms into place (unroll-2 elides the movs)
            w[0]=qa.x; w[1]=qa.y; w[2]=qa.z;  w[3]=qa.w;
            w[4]=qb.x; w[5]=qb.y; w[6]=qb.z;  w[7]=qb.w;
            w[8]=qc.x; w[9]=qc.y; w[10]=qc.z; w[11]=qc.w;
            #pragma unroll
            for (int j = 0; j < 6; ++j) lv[j] = lvn[j];
        }

        __syncthreads();   // writes visible before next iteration's gathers
    }

    // ---- final marginalization: variable tid (the 512 output vars), 4 rows ----
    {
        int f0 = final_idx[3*tid], f1 = final_idx[3*tid + 1], f2 = final_idx[3*tid + 2];
        v4f d0 = Ad[pslot(f0)];
        v4f d1 = Ad[pslot(f1)];
        v4f d2 = Ad[pslot(f2)];
        float wf0 = w_final[3*tid], wf1 = w_final[3*tid + 1], wf2 = w_final[3*tid + 2];
        float lf  = llr_final[tid];
        v4f l;
        l.x = llr[(b0 + 0) * NVAR + tid];
        l.y = llr[(b0 + 1) * NVAR + tid];
        l.z = llr[(b0 + 2) * NVAR + tid];
        l.w = llr[(b0 + 3) * NVAR + tid];

        v4f fin = (d0 * wf0 + d1 * wf1 + d2 * wf2) * LN2;   // c2v = ln2 * d
        v4f v   = l * lf + fin;
        out[(b0 + 0) * NOUT + tid] = fast_rcp(1.f + fast_exp2(-v.x * LOG2E));
        out[(b0 + 1) * NOUT + tid] = fast_rcp(1.f + fast_exp2(-v.y * LOG2E));
        out[(b0 + 2) * NOUT + tid] = fast_rcp(1.f + fast_exp2(-v.z * LOG2E));
        out[(b0 + 3) * NOUT + tid] = fast_rcp(1.f + fast_exp2(-v.w * LOG2E));
    }
}

} // namespace

extern "C" void kernel_launch(void* const* d_in, const int* in_sizes, int n_in,
                              void* d_out, int out_size, void* d_ws, size_t ws_size,
                              hipStream_t stream)
{
    const float* llr       = (const float*)d_in[0];
    const float* w_iter    = (const float*)d_in[1];
    const float* llr_iter  = (const float*)d_in[2];
    const float* w_final   = (const float*)d_in[3];
    const float* llr_final = (const float*)d_in[4];
    const int*   v_sum_idx = (const int*)d_in[5];
    // d_in[6] = c_prod_idx: unused (check groups are consecutive by construction)
    const int*   edge_var  = (const int*)d_in[7];
    const int*   final_idx = (const int*)d_in[8];
    float* outp = (float*)d_out;

    dim3 grid(BATCH / ROWS), block(T);
    hipLaunchKernelGGL(bp_decode, grid, block, 0, stream,
                       llr, w_iter, llr_iter, w_final, llr_final,
                       v_sum_idx, edge_var, final_idx, outp);
}